// Round 12
// baseline (109.870 us; speedup 1.0000x reference)
//
#include <hip/hip_runtime.h>
#include <hip/hip_bf16.h>
#include <math.h>

// NT-Xent loss. N=8192 rows, D=256. Two dispatches:
//   k_prep  : row L2-norm fp32->bf16 (ws), posv[i] = (1-pos_i)/T, zero sumexp
//   k_simfin: R7 hot loop + wave-private-LDS csum (per-tile flush) +
//             last-block finisher stores out[0].
// History: R9 split 123.8 | R12 fused 250 (fence storm) | R13 fused 150.6
//   (hot loop degraded inside big kernel) | R14 two-dispatch 107.9 BEST
//   (k_simfin 52.4; gaps ~7.5).
// R15: remove the per-strip contended global csum atomics (R6/R7 data:
//   they took per-strip period 2.95 -> 5.03 us; R11's LDS-atomicAdd fix
//   failed because HIP compiles shared-mem atomicAdd to a CAS loop).
//   CAS-free scheme: each wave PLAIN-STORES its csum partial to a
//   wave-private LDS slot (each (w,jt,col) cell written exactly once per
//   tile); per-tile flush = raw lgkmcnt(0)+s_barrier (no vmcnt drain ->
//   in-flight STAGE untouched), each thread sums 4 slots for its column,
//   ONE global atomic, re-zero, second raw barrier. 4x fewer csum
//   lane-atomics, moved off the per-strip critical path.
#define N_ROWS 8192
#define D_DIM  256
#define HALF_N 4096
#define NBLK   512
#define INV_T      14.285714285714286f      // 1/0.07
#define SCALE_LOG2 20.609929155556620f      // log2(e)/0.07
#define NEG_SCALE  -20.609929155556620f
#define EPSV   1e-8f

typedef __attribute__((ext_vector_type(8))) short bf16x8;   // 8 bf16 = 4 VGPR
typedef __attribute__((ext_vector_type(4))) float f32x4;

#define AS1 __attribute__((address_space(1)))
#define AS3 __attribute__((address_space(3)))
#define AGT __HIP_MEMORY_SCOPE_AGENT

__device__ unsigned g_done = 0;    // k_simfin arrivals (monotonic forever;
                                   // & (NBLK-1) selects last arrival/iter)

__device__ inline unsigned short f2bf(float x) {
    unsigned int u = __float_as_uint(x);
    unsigned int r = (u + 0x7fffu + ((u >> 16) & 1u)) >> 16;   // RNE
    return (unsigned short)r;
}

// ------- kernel 1: normalize -> bf16; posv; zero sumexp --------------------
__global__ __launch_bounds__(256) void k_prep(const float* __restrict__ feat,
                                              unsigned short* __restrict__ fbf,
                                              float* __restrict__ sumexp,
                                              float* __restrict__ posv) {
    const int tid = threadIdx.x, w = tid >> 6, lane = tid & 63;
    const int row = blockIdx.x * 4 + w;              // 2048 blocks * 4 rows
    const int pc  = (row + HALF_N) & (N_ROWS - 1);

    const float4 v = ((const float4*)(feat + row * D_DIM))[lane];
    const float4 c = ((const float4*)(feat + pc  * D_DIM))[lane];
    float ss  = v.x*v.x + v.y*v.y + v.z*v.z + v.w*v.w;   // ||a||^2
    float dab = v.x*c.x + v.y*c.y + v.z*c.z + v.w*c.w;
    float dbb = c.x*c.x + c.y*c.y + c.z*c.z + c.w*c.w;
    #pragma unroll
    for (int off = 32; off; off >>= 1) {
        ss  += __shfl_xor(ss,  off);
        dab += __shfl_xor(dab, off);
        dbb += __shfl_xor(dbb, off);
    }
    const float na = fmaxf(sqrtf(ss), EPSV);
    const float sc = 1.f / na;
    ushort4 o;
    o.x = f2bf(v.x * sc); o.y = f2bf(v.y * sc);
    o.z = f2bf(v.z * sc); o.w = f2bf(v.w * sc);
    ((ushort4*)(fbf + row * D_DIM))[lane] = o;
    if (lane == 0)
        posv[row] = INV_T - (dab / (na * fmaxf(sqrtf(dbb), EPSV))) * INV_T;
    if (tid < 4) sumexp[blockIdx.x * 4 + tid] = 0.f;
}

// ------- kernel 2: sim + exp + row/col sums (symmetric) + finisher ---------
// Work unit = strip (tile tt, jt): 256 rows x 32 cols, tt over the 528
// upper-triangle 256x256 tiles (rt >= cs), jt in [0,8). 4224 strips,
// block b owns [(33b)>>2, (33(b+1))>>2). 4 waves x 64 rows; A in regs
// (128 VGPR). B strip = 16 KB LDS via global_load_lds w=16, XOR-16B-chunk
// swizzle. Off-diag: rsum in regs; csum partial per wave -> PLAIN ds_write
// to csumLds[w][jt*32 + q*16 + l15] (each cell written once per tile).
// Tile boundary: raw lgkmcnt+s_barrier, thread tid sums 4 slots of col tid,
// 1 atomicAdd, zero, raw barrier; then rsum flush + A reload.
__global__ __launch_bounds__(256, 2) void k_simfin(const unsigned short* __restrict__ fbf,
                                                   float* __restrict__ sumexp,
                                                   const float* __restrict__ posv,
                                                   float* __restrict__ out) {
    __shared__ __align__(16) char Bs[16384];
    __shared__ float csumLds[1024];                // [wave][256 cols]
    __shared__ float red[4];
    __shared__ int lastBlk;
    const int tid  = threadIdx.x;
    const int lane = tid & 63;
    const int w    = tid >> 6;
    const int q    = lane >> 4, l15 = lane & 15;

    int g          = (33 * blockIdx.x) >> 2;          // first strip
    const int gEnd = (33 * (blockIdx.x + 1)) >> 2;    // one past last

    const int tt0 = g >> 3;
    int rt = (int)((sqrtf(8.f * (float)tt0 + 1.f) - 1.f) * 0.5f);
    while ((rt + 1) * (rt + 2) / 2 <= tt0) ++rt;
    while (rt * (rt + 1) / 2 > tt0) --rt;
    int cs = tt0 - rt * (rt + 1) / 2;
    int jt = g & 7;

#define STAGE(colRow0) do {                                                   \
        const char* Bg_ = (const char*)fbf + (size_t)(colRow0) * 512;         \
        _Pragma("unroll")                                                     \
        for (int i_ = 0; i_ < 4; ++i_) {                                      \
            const int idx_ = i_ * 256 + tid;                                  \
            const int col_ = idx_ >> 5;                                       \
            const int cir_ = idx_ & 31;                                       \
            __builtin_amdgcn_global_load_lds(                                 \
                (const AS1 void*)(Bg_ + col_ * 512 + ((cir_ ^ (col_ & 7)) << 4)), \
                (AS3 void*)(Bs + idx_ * 16), 16, 0, 0);                       \
        }                                                                     \
    } while (0)

    bf16x8 afrag[8][4];
#define LOAD_A(rt_) do {                                                      \
        const int rowBase_ = (rt_) * 256 + w * 64;                            \
        _Pragma("unroll")                                                     \
        for (int t_ = 0; t_ < 8; ++t_)                                        \
            _Pragma("unroll")                                                 \
            for (int ri_ = 0; ri_ < 4; ++ri_)                                 \
                afrag[t_][ri_] = *(const bf16x8*)(fbf                         \
                    + (rowBase_ + ri_*16 + l15) * D_DIM + t_*32 + q*8);       \
    } while (0)

    float rsum[4][4];
#define ZERO_RSUM() do {                                                      \
        _Pragma("unroll")                                                     \
        for (int ri_ = 0; ri_ < 4; ++ri_)                                     \
            _Pragma("unroll")                                                 \
            for (int r_ = 0; r_ < 4; ++r_) rsum[ri_][r_] = 0.f;               \
    } while (0)

#define FLUSH_RSUM(rt_) do {                                                  \
        const int rowBase_ = (rt_) * 256 + w * 64;                            \
        _Pragma("unroll")                                                     \
        for (int ri_ = 0; ri_ < 4; ++ri_)                                     \
            _Pragma("unroll")                                                 \
            for (int r_ = 0; r_ < 4; ++r_) {                                  \
                float s_ = rsum[ri_][r_];                                     \
                s_ += __shfl_xor(s_, 1);                                      \
                s_ += __shfl_xor(s_, 2);                                      \
                s_ += __shfl_xor(s_, 4);                                      \
                s_ += __shfl_xor(s_, 8);                                      \
                if (l15 == 0)                                                 \
                    atomicAdd(&sumexp[rowBase_ + ri_ * 16 + q * 4 + r_], s_); \
            }                                                                 \
    } while (0)

    // per-tile csum flush: all waves' ds_writes for tile (cs_) must be in.
    // Raw barriers only (no vmcnt drain -> in-flight STAGE unaffected).
#define FLUSH_CSUM(cs_, offd_) do {                                           \
        asm volatile("s_waitcnt lgkmcnt(0)" ::: "memory");                    \
        __builtin_amdgcn_s_barrier();                                         \
        __builtin_amdgcn_sched_barrier(0);                                    \
        if (offd_) {                                                          \
            const float s_ = csumLds[tid] + csumLds[tid + 256]                \
                           + csumLds[tid + 512] + csumLds[tid + 768];         \
            atomicAdd(&sumexp[(cs_) * 256 + tid], s_);                        \
        }                                                                     \
        csumLds[tid]       = 0.f;                                             \
        csumLds[tid + 256] = 0.f;                                             \
        csumLds[tid + 512] = 0.f;                                             \
        csumLds[tid + 768] = 0.f;                                             \
        asm volatile("s_waitcnt lgkmcnt(0)" ::: "memory");                    \
        __builtin_amdgcn_s_barrier();                                         \
        __builtin_amdgcn_sched_barrier(0);                                    \
    } while (0)

    STAGE(cs * 256 + jt * 32);
    LOAD_A(rt);
    ZERO_RSUM();
    csumLds[tid]       = 0.f;
    csumLds[tid + 256] = 0.f;
    csumLds[tid + 512] = 0.f;
    csumLds[tid + 768] = 0.f;

    while (true) {
        const int colBase = cs * 256 + jt * 32;
        const bool isDiag = (rt == cs);
        const int rowBase = rt * 256 + w * 64;

        __syncthreads();                           // DMA of strip g drained

        f32x4 acc[4][2];
        #pragma unroll
        for (int ri = 0; ri < 4; ++ri)
            #pragma unroll
            for (int ci = 0; ci < 2; ++ci) acc[ri][ci] = (f32x4){0.f, 0.f, 0.f, 0.f};

        #pragma unroll
        for (int t = 0; t < 8; ++t) {
            bf16x8 bfrag[2];
            #pragma unroll
            for (int ci = 0; ci < 2; ++ci) {
                const int c   = ci * 16 + l15;     // local col 0..31
                const int cir = t * 4 + q;         // k-chunk
                bfrag[ci] = *(const bf16x8*)(Bs + c * 512 + ((cir ^ (c & 7)) << 4));
            }
            #pragma unroll
            for (int ri = 0; ri < 4; ++ri)
                #pragma unroll
                for (int ci = 0; ci < 2; ++ci)
                    acc[ri][ci] = __builtin_amdgcn_mfma_f32_16x16x32_bf16(
                        afrag[t][ri], bfrag[ci], acc[ri][ci], 0, 0, 0);
        }

        const bool more = (g + 1 < gEnd);
        int nrt = rt, ncs = cs, njt = jt + 1;
        if (njt == 8) {
            njt = 0; ncs = cs + 1;
            if (ncs > rt) { nrt = rt + 1; ncs = 0; }
        }

        if (more) {
            __syncthreads();                       // all waves done reading Bs
            STAGE(ncs * 256 + njt * 32);
            if (njt == 0) LOAD_A(nrt);             // reload hides under exp
        }

        if (isDiag) {
            #pragma unroll
            for (int ri = 0; ri < 4; ++ri) {
                const int trow = rowBase + ri * 16;
                #pragma unroll
                for (int ci = 0; ci < 2; ++ci) {
                    const int tcol = colBase + ci * 16;
                    if (trow == tcol) {            // diagonal 16x16 tile
                        #pragma unroll
                        for (int r = 0; r < 4; ++r) {
                            const float e = __builtin_amdgcn_exp2f(
                                __builtin_fmaf(acc[ri][ci][r], SCALE_LOG2, NEG_SCALE));
                            rsum[ri][r] += (q * 4 + r == l15) ? 0.f : e;
                        }
                    } else {
                        #pragma unroll
                        for (int r = 0; r < 4; ++r)
                            rsum[ri][r] += __builtin_amdgcn_exp2f(
                                __builtin_fmaf(acc[ri][ci][r], SCALE_LOG2, NEG_SCALE));
                    }
                }
            }
        } else {
            // off-diag: rsum in regs; csum partial -> wave-private LDS slot
            float csum0 = 0.f, csum1 = 0.f;
            #pragma unroll
            for (int ri = 0; ri < 4; ++ri) {
                #pragma unroll
                for (int r = 0; r < 4; ++r) {
                    const float e0 = __builtin_amdgcn_exp2f(
                        __builtin_fmaf(acc[ri][0][r], SCALE_LOG2, NEG_SCALE));
                    const float e1 = __builtin_amdgcn_exp2f(
                        __builtin_fmaf(acc[ri][1][r], SCALE_LOG2, NEG_SCALE));
                    rsum[ri][r] += e0 + e1;
                    csum0 += e0;
                    csum1 += e1;
                }
            }
            // reduce over the 4 q-groups (all lanes end up with the total)
            csum0 += __shfl_xor(csum0, 16); csum0 += __shfl_xor(csum0, 32);
            csum1 += __shfl_xor(csum1, 16); csum1 += __shfl_xor(csum1, 32);
            // one plain ds_write, 32 active lanes, conflict-free
            if (q < 2)
                csumLds[w * 256 + jt * 32 + q * 16 + l15] = q ? csum1 : csum0;
        }

        if (!more) break;
        if (njt == 0) {                            // crossed a tile boundary
            FLUSH_CSUM(cs, rt != cs);              // per-tile, off strip path
            FLUSH_RSUM(rt);
            ZERO_RSUM();
        }
        rt = nrt; cs = ncs; jt = njt; ++g;
    }

    // tail: flush last (possibly partial) tile
    {
        asm volatile("s_waitcnt lgkmcnt(0)" ::: "memory");
        __builtin_amdgcn_s_barrier();
        __builtin_amdgcn_sched_barrier(0);
        if (rt != cs) {
            const float s_ = csumLds[tid] + csumLds[tid + 256]
                           + csumLds[tid + 512] + csumLds[tid + 768];
            atomicAdd(&sumexp[cs * 256 + tid], s_);
        }
    }
    FLUSH_RSUM(rt);
#undef STAGE
#undef LOAD_A
#undef ZERO_RSUM
#undef FLUSH_RSUM
#undef FLUSH_CSUM

    // ---- finisher: last arriving block computes the mean -----------------
    __syncthreads();                               // drain this block's atomics
    if (tid == 0) {
        const unsigned old = __hip_atomic_fetch_add(&g_done, 1u, __ATOMIC_ACQ_REL, AGT);
        lastBlk = ((old & (NBLK - 1)) == NBLK - 1);
    }
    __syncthreads();
    if (lastBlk) {
        // acquire above: all 511 prior blocks' sumexp atomics visible; L1
        // invalidated -> plain loads fresh (R13/R14-proven, absmax 0.0).
        float wsum = 0.f;
        for (int i = tid; i < N_ROWS; i += 256)
            wsum += posv[i] + logf(sumexp[i]);
        #pragma unroll
        for (int off = 32; off; off >>= 1) wsum += __shfl_xor(wsum, off);
        if (lane == 0) red[w] = wsum;
        __syncthreads();
        if (tid == 0)
            out[0] = (red[0] + red[1] + red[2] + red[3]) * (1.f / N_ROWS);
    }
}

extern "C" void kernel_launch(void* const* d_in, const int* in_sizes, int n_in,
                              void* d_out, int out_size, void* d_ws, size_t ws_size,
                              hipStream_t stream) {
    const float* feat = (const float*)d_in[0];
    char* ws = (char*)d_ws;
    unsigned short* fbf = (unsigned short*)ws;                       // 4 MB bf16
    float* sumexp = (float*)(ws + 4u * 1024u * 1024u);               // 32 KB
    float* posv   = (float*)(ws + 4u * 1024u * 1024u + 32768u);      // 32 KB

    k_prep  <<<N_ROWS / 4, 256, 0, stream>>>(feat, fbf, sumexp, posv);
    k_simfin<<<NBLK,       256, 0, stream>>>(fbf, sumexp, posv, (float*)d_out);
}

// Round 13
// 108.276 us; speedup vs baseline: 1.0147x; 1.0147x over previous
//
#include <hip/hip_runtime.h>
#include <hip/hip_bf16.h>
#include <math.h>

// NT-Xent loss. N=8192 rows, D=256. Two dispatches:
//   k_prep  : row L2-norm fp32->bf16 (ws), posv[i] = (1-pos_i)/T, zero sumexp
//   k_simfin: R7 hot loop (symmetry, 512 balanced persistent blocks) +
//             last-block finisher (device-global arrival counter) -> out[0].
// SESSION SUMMARY (totals): R3 131.9 | R5 130.0 | R6 125.0 | R7 124.2 |
//   R9 123.8 | R14 107.9 BEST | R15 109.9.
// Tested and REFUTED for the hot loop's ~26%-util stall: LDS double-buffer
//   (R4, -16%), LDS traffic halving (R5, -2us only), tail quantization (R7,
//   null), direct-global B (R8, -20%), counted-vmcnt 2-deep pipeline (R9,
//   null), 3 waves/SIMD occupancy (R10, regression), LDS-atomic csum (R11,
//   CAS-loop disaster), full fusion (R12 fence storm; R13 codegen
//   degradation), contended-global-atomic removal (R15, +2us).
// Wins: symmetry + strip-balanced persistence (R6/R7), k_nll fusion into
//   k_simfin's last-block finisher + launch-gap elimination (R14, -16us).
// Remaining budget at 107.9: harness fill 44 (uncontrollable) + k_prep 4 +
//   k_simfin 52.4 + gaps 7.5. This file is R14 verbatim (session best).
#define N_ROWS 8192
#define D_DIM  256
#define HALF_N 4096
#define NBLK   512
#define INV_T      14.285714285714286f      // 1/0.07
#define SCALE_LOG2 20.609929155556620f      // log2(e)/0.07
#define NEG_SCALE  -20.609929155556620f
#define EPSV   1e-8f

typedef __attribute__((ext_vector_type(8))) short bf16x8;   // 8 bf16 = 4 VGPR
typedef __attribute__((ext_vector_type(4))) float f32x4;

#define AS1 __attribute__((address_space(1)))
#define AS3 __attribute__((address_space(3)))
#define AGT __HIP_MEMORY_SCOPE_AGENT

__device__ unsigned g_done = 0;    // k_simfin arrivals (monotonic forever;
                                   // & (NBLK-1) selects last arrival/iter)

__device__ inline unsigned short f2bf(float x) {
    unsigned int u = __float_as_uint(x);
    unsigned int r = (u + 0x7fffu + ((u >> 16) & 1u)) >> 16;   // RNE
    return (unsigned short)r;
}

// ------- kernel 1: normalize -> bf16; posv; zero sumexp --------------------
__global__ __launch_bounds__(256) void k_prep(const float* __restrict__ feat,
                                              unsigned short* __restrict__ fbf,
                                              float* __restrict__ sumexp,
                                              float* __restrict__ posv) {
    const int tid = threadIdx.x, w = tid >> 6, lane = tid & 63;
    const int row = blockIdx.x * 4 + w;              // 2048 blocks * 4 rows
    const int pc  = (row + HALF_N) & (N_ROWS - 1);

    const float4 v = ((const float4*)(feat + row * D_DIM))[lane];
    const float4 c = ((const float4*)(feat + pc  * D_DIM))[lane];
    float ss  = v.x*v.x + v.y*v.y + v.z*v.z + v.w*v.w;   // ||a||^2
    float dab = v.x*c.x + v.y*c.y + v.z*c.z + v.w*c.w;
    float dbb = c.x*c.x + c.y*c.y + c.z*c.z + c.w*c.w;
    #pragma unroll
    for (int off = 32; off; off >>= 1) {
        ss  += __shfl_xor(ss,  off);
        dab += __shfl_xor(dab, off);
        dbb += __shfl_xor(dbb, off);
    }
    const float na = fmaxf(sqrtf(ss), EPSV);
    const float sc = 1.f / na;
    ushort4 o;
    o.x = f2bf(v.x * sc); o.y = f2bf(v.y * sc);
    o.z = f2bf(v.z * sc); o.w = f2bf(v.w * sc);
    ((ushort4*)(fbf + row * D_DIM))[lane] = o;
    if (lane == 0)
        posv[row] = INV_T - (dab / (na * fmaxf(sqrtf(dbb), EPSV))) * INV_T;
    if (tid < 4) sumexp[blockIdx.x * 4 + tid] = 0.f;
}

// ------- kernel 2: R7 k_sim body (verbatim) + last-block finisher ----------
// Work unit = strip (tile tt, jt): 256 rows x 32 cols, tt over the 528
// upper-triangle 256x256 tiles (rt >= cs), jt in [0,8). 4224 strips,
// block b owns [(33b)>>2, (33(b+1))>>2). 4 waves x 64 rows; A in regs
// (128 VGPR). B strip = 16 KB LDS via global_load_lds w=16, XOR-16B-chunk
// swizzle. Off-diag: rsum in regs + csum per strip (shfl + atomicAdd).
// Tail: syncthreads (drain atomics) -> g_done ACQ_REL; last arrival's
// acquire makes all 511 other blocks' sumexp atomics visible (R13-proven),
// sums posv[i]+log(sumexp[i]) over 8192 rows, stores out[0].
__global__ __launch_bounds__(256, 2) void k_simfin(const unsigned short* __restrict__ fbf,
                                                   float* __restrict__ sumexp,
                                                   const float* __restrict__ posv,
                                                   float* __restrict__ out) {
    __shared__ __align__(16) char Bs[16384];
    __shared__ float red[4];
    __shared__ int lastBlk;
    const int tid  = threadIdx.x;
    const int lane = tid & 63;
    const int w    = tid >> 6;
    const int q    = lane >> 4, l15 = lane & 15;

    int g          = (33 * blockIdx.x) >> 2;          // first strip
    const int gEnd = (33 * (blockIdx.x + 1)) >> 2;    // one past last

    const int tt0 = g >> 3;
    int rt = (int)((sqrtf(8.f * (float)tt0 + 1.f) - 1.f) * 0.5f);
    while ((rt + 1) * (rt + 2) / 2 <= tt0) ++rt;
    while (rt * (rt + 1) / 2 > tt0) --rt;
    int cs = tt0 - rt * (rt + 1) / 2;
    int jt = g & 7;

#define STAGE(colRow0) do {                                                   \
        const char* Bg_ = (const char*)fbf + (size_t)(colRow0) * 512;         \
        _Pragma("unroll")                                                     \
        for (int i_ = 0; i_ < 4; ++i_) {                                      \
            const int idx_ = i_ * 256 + tid;                                  \
            const int col_ = idx_ >> 5;                                       \
            const int cir_ = idx_ & 31;                                       \
            __builtin_amdgcn_global_load_lds(                                 \
                (const AS1 void*)(Bg_ + col_ * 512 + ((cir_ ^ (col_ & 7)) << 4)), \
                (AS3 void*)(Bs + idx_ * 16), 16, 0, 0);                       \
        }                                                                     \
    } while (0)

    bf16x8 afrag[8][4];
#define LOAD_A(rt_) do {                                                      \
        const int rowBase_ = (rt_) * 256 + w * 64;                            \
        _Pragma("unroll")                                                     \
        for (int t_ = 0; t_ < 8; ++t_)                                        \
            _Pragma("unroll")                                                 \
            for (int ri_ = 0; ri_ < 4; ++ri_)                                 \
                afrag[t_][ri_] = *(const bf16x8*)(fbf                         \
                    + (rowBase_ + ri_*16 + l15) * D_DIM + t_*32 + q*8);       \
    } while (0)

    float rsum[4][4];
#define ZERO_RSUM() do {                                                      \
        _Pragma("unroll")                                                     \
        for (int ri_ = 0; ri_ < 4; ++ri_)                                     \
            _Pragma("unroll")                                                 \
            for (int r_ = 0; r_ < 4; ++r_) rsum[ri_][r_] = 0.f;               \
    } while (0)

#define FLUSH_RSUM(rt_) do {                                                  \
        const int rowBase_ = (rt_) * 256 + w * 64;                            \
        _Pragma("unroll")                                                     \
        for (int ri_ = 0; ri_ < 4; ++ri_)                                     \
            _Pragma("unroll")                                                 \
            for (int r_ = 0; r_ < 4; ++r_) {                                  \
                float s_ = rsum[ri_][r_];                                     \
                s_ += __shfl_xor(s_, 1);                                      \
                s_ += __shfl_xor(s_, 2);                                      \
                s_ += __shfl_xor(s_, 4);                                      \
                s_ += __shfl_xor(s_, 8);                                      \
                if (l15 == 0)                                                 \
                    atomicAdd(&sumexp[rowBase_ + ri_ * 16 + q * 4 + r_], s_); \
            }                                                                 \
    } while (0)

    STAGE(cs * 256 + jt * 32);
    LOAD_A(rt);
    ZERO_RSUM();

    while (true) {
        const int colBase = cs * 256 + jt * 32;
        const bool isDiag = (rt == cs);
        const int rowBase = rt * 256 + w * 64;

        __syncthreads();                           // DMA of strip g drained

        f32x4 acc[4][2];
        #pragma unroll
        for (int ri = 0; ri < 4; ++ri)
            #pragma unroll
            for (int ci = 0; ci < 2; ++ci) acc[ri][ci] = (f32x4){0.f, 0.f, 0.f, 0.f};

        #pragma unroll
        for (int t = 0; t < 8; ++t) {
            bf16x8 bfrag[2];
            #pragma unroll
            for (int ci = 0; ci < 2; ++ci) {
                const int c   = ci * 16 + l15;     // local col 0..31
                const int cir = t * 4 + q;         // k-chunk
                bfrag[ci] = *(const bf16x8*)(Bs + c * 512 + ((cir ^ (c & 7)) << 4));
            }
            #pragma unroll
            for (int ri = 0; ri < 4; ++ri)
                #pragma unroll
                for (int ci = 0; ci < 2; ++ci)
                    acc[ri][ci] = __builtin_amdgcn_mfma_f32_16x16x32_bf16(
                        afrag[t][ri], bfrag[ci], acc[ri][ci], 0, 0, 0);
        }

        const bool more = (g + 1 < gEnd);
        int nrt = rt, ncs = cs, njt = jt + 1;
        if (njt == 8) {
            njt = 0; ncs = cs + 1;
            if (ncs > rt) { nrt = rt + 1; ncs = 0; }
        }

        if (more) {
            __syncthreads();                       // all waves done reading Bs
            STAGE(ncs * 256 + njt * 32);
            if (njt == 0) LOAD_A(nrt);             // reload hides under exp
        }

        if (isDiag) {
            #pragma unroll
            for (int ri = 0; ri < 4; ++ri) {
                const int trow = rowBase + ri * 16;
                #pragma unroll
                for (int ci = 0; ci < 2; ++ci) {
                    const int tcol = colBase + ci * 16;
                    if (trow == tcol) {            // diagonal 16x16 tile
                        #pragma unroll
                        for (int r = 0; r < 4; ++r) {
                            const float e = __builtin_amdgcn_exp2f(
                                __builtin_fmaf(acc[ri][ci][r], SCALE_LOG2, NEG_SCALE));
                            rsum[ri][r] += (q * 4 + r == l15) ? 0.f : e;
                        }
                    } else {
                        #pragma unroll
                        for (int r = 0; r < 4; ++r)
                            rsum[ri][r] += __builtin_amdgcn_exp2f(
                                __builtin_fmaf(acc[ri][ci][r], SCALE_LOG2, NEG_SCALE));
                    }
                }
            }
        } else {
            float csum0 = 0.f, csum1 = 0.f;
            #pragma unroll
            for (int ri = 0; ri < 4; ++ri) {
                #pragma unroll
                for (int r = 0; r < 4; ++r) {
                    const float e0 = __builtin_amdgcn_exp2f(
                        __builtin_fmaf(acc[ri][0][r], SCALE_LOG2, NEG_SCALE));
                    const float e1 = __builtin_amdgcn_exp2f(
                        __builtin_fmaf(acc[ri][1][r], SCALE_LOG2, NEG_SCALE));
                    rsum[ri][r] += e0 + e1;
                    csum0 += e0;
                    csum1 += e1;
                }
            }
            csum0 += __shfl_xor(csum0, 16); csum0 += __shfl_xor(csum0, 32);
            csum1 += __shfl_xor(csum1, 16); csum1 += __shfl_xor(csum1, 32);
            if (q == 0)      atomicAdd(&sumexp[colBase      + l15], csum0);
            else if (q == 1) atomicAdd(&sumexp[colBase + 16 + l15], csum1);
        }

        if (!more) break;
        if (njt == 0) {                            // crossed a tile boundary
            FLUSH_RSUM(rt);
            ZERO_RSUM();
        }
        rt = nrt; cs = ncs; jt = njt; ++g;
    }

    FLUSH_RSUM(rt);
#undef STAGE
#undef LOAD_A
#undef ZERO_RSUM
#undef FLUSH_RSUM

    // ---- finisher: last arriving block computes the mean -----------------
    __syncthreads();                               // drain this block's atomics
    if (tid == 0) {
        const unsigned old = __hip_atomic_fetch_add(&g_done, 1u, __ATOMIC_ACQ_REL, AGT);
        lastBlk = ((old & (NBLK - 1)) == NBLK - 1);
    }
    __syncthreads();
    if (lastBlk) {
        // acquire above: all 511 prior blocks' sumexp atomics visible; L1
        // invalidated -> plain loads fresh (R13/R14-proven, absmax 0.0).
        float wsum = 0.f;
        for (int i = tid; i < N_ROWS; i += 256)
            wsum += posv[i] + logf(sumexp[i]);
        #pragma unroll
        for (int off = 32; off; off >>= 1) wsum += __shfl_xor(wsum, off);
        if (lane == 0) red[w] = wsum;
        __syncthreads();
        if (tid == 0)
            out[0] = (red[0] + red[1] + red[2] + red[3]) * (1.f / N_ROWS);
    }
}

extern "C" void kernel_launch(void* const* d_in, const int* in_sizes, int n_in,
                              void* d_out, int out_size, void* d_ws, size_t ws_size,
                              hipStream_t stream) {
    const float* feat = (const float*)d_in[0];
    char* ws = (char*)d_ws;
    unsigned short* fbf = (unsigned short*)ws;                       // 4 MB bf16
    float* sumexp = (float*)(ws + 4u * 1024u * 1024u);               // 32 KB
    float* posv   = (float*)(ws + 4u * 1024u * 1024u + 32768u);      // 32 KB

    k_prep  <<<N_ROWS / 4, 256, 0, stream>>>(feat, fbf, sumexp, posv);
    k_simfin<<<NBLK,       256, 0, stream>>>(fbf, sumexp, posv, (float*)d_out);
}